// Round 4
// baseline (178.235 us; speedup 1.0000x reference)
//
#include <hip/hip_runtime.h>
#include <hip/hip_bf16.h>
#include <stdint.h>

#define PDIM 4096
#define KSEL 3687.0f
#define NITER 50

typedef unsigned short ushort_t;
typedef __attribute__((ext_vector_type(8))) __bf16 bf16x8;
typedef __attribute__((ext_vector_type(4))) float f32x4;

typedef __attribute__((address_space(3))) void lds_void;
typedef __attribute__((address_space(1))) const void glob_void;

__device__ __forceinline__ ushort_t f32_to_bf16_rne(float f) {
  union { float f; uint32_t u; } v; v.f = f;
  uint32_t r = 0x7FFFu + ((v.u >> 16) & 1u);
  return (ushort_t)((v.u + r) >> 16);
}

__device__ __forceinline__ void async_cp16(const void* g, void* l) {
  __builtin_amdgcn_global_load_lds((glob_void*)g, (lds_void*)l, 16, 0, 0);
}

// ---------------- Kernel 1: fused Dykstra (block 0) + x->bf16 (rest) ------
// Dykstra: p = t - y = -corr is lane-uniform -> keep p as a scalar.
__global__ __launch_bounds__(256) void prep_kernel(
    const float* __restrict__ alpha, float* __restrict__ a_out,
    const float* __restrict__ x, ushort_t* __restrict__ Xb, int n4) {
  if (blockIdx.x != 0) {
    const int i = (blockIdx.x - 1) * 256 + threadIdx.x;
    if (i < n4) {
      const float4 v = ((const float4*)x)[i];
      ushort4 o;
      o.x = f32_to_bf16_rne(v.x);
      o.y = f32_to_bf16_rne(v.y);
      o.z = f32_to_bf16_rne(v.z);
      o.w = f32_to_bf16_rne(v.w);
      ((ushort4*)Xb)[i] = o;
    }
    return;
  }
  __shared__ float red[8];
  const int tid = threadIdx.x;
  const int lane = tid & 63;
  const int wv = tid >> 6;
  float xx[16], q[16];
  float p = 0.0f;
#pragma unroll
  for (int i = 0; i < 16; ++i) {
    xx[i] = alpha[i * 256 + tid] * 100.0f;  // s = alpha / 0.01
    q[i] = 0.0f;
  }
  for (int it = 0; it < NITER; ++it) {
    float t[16];
    float loc = 0.0f;
#pragma unroll
    for (int i = 0; i < 16; ++i) { t[i] = xx[i] + p; loc += t[i]; }
#pragma unroll
    for (int off = 32; off > 0; off >>= 1) loc += __shfl_down(loc, off, 64);
    const int slot = (it & 1) * 4;
    if (lane == 0) red[slot + wv] = loc;
    __syncthreads();
    const float tot = red[slot] + red[slot + 1] + red[slot + 2] + red[slot + 3];
    const float corr = (KSEL - tot) * (1.0f / 4096.0f);
    p = -corr;
#pragma unroll
    for (int i = 0; i < 16; ++i) {
      const float y = t[i] + corr;
      const float u = y + q[i];
      const float xn = fminf(fmaxf(u, 0.0f), 1.0f);
      q[i] = u - xn;
      xx[i] = xn;
    }
  }
#pragma unroll
  for (int i = 0; i < 16; ++i) a_out[i * 256 + tid] = xx[i];
}

// ---------------- Kernel 2: materialize W (row-major bf16) ----------------
// W[r][c] = a[(r-c) mod 4096] * V[(r-c) mod 4096][c]
// 256x32 W tile: band = 287 rows -> 1.12x read amplification (was 1.49x).
// LDS pad 34 -> phase-2 diagonal reads are <=2-way (free).
__global__ __launch_bounds__(256) void wmat_kernel(
    const float* __restrict__ V, const float* __restrict__ a,
    ushort_t* __restrict__ Wb) {
  __shared__ float vt[287][34];
  const int t = threadIdx.x;
  const int r0 = blockIdx.x * 256;
  const int c0 = blockIdx.y * 32;
  const int dbase = (r0 - c0 - 31 + 2 * PDIM) & (PDIM - 1);
  // phase 1: load 287 x 32 fp32 band (32 rows/pass, 8 lanes x float4 per row)
  const int cs = (t & 7) * 4;
  const int rsub = t >> 3;
#pragma unroll
  for (int i = 0; i < 9; ++i) {
    const int ld = i * 32 + rsub;
    if (ld < 287) {
      const int d = (dbase + ld) & (PDIM - 1);
      const float av = a[d];
      const float4 vv = *(const float4*)(V + (size_t)d * PDIM + c0 + cs);
      vt[ld][cs + 0] = av * vv.x;
      vt[ld][cs + 1] = av * vv.y;
      vt[ld][cs + 2] = av * vv.z;
      vt[ld][cs + 3] = av * vv.w;
    }
  }
  __syncthreads();
  // phase 2: diagonal gather -> pack bf16x8 -> 16B store
  // 4 lanes/row (64B contiguous), 64 rows/pass, 4 passes.
  const int cb = (t & 3) * 8;
#pragma unroll
  for (int k = 0; k < 4; ++k) {
    const int ry = k * 64 + (t >> 2);
    ushort_t pk[8];
#pragma unroll
    for (int j = 0; j < 8; ++j) {
      const int c = cb + j;
      pk[j] = f32_to_bf16_rne(vt[ry - c + 31][c]);
    }
    *(uint4*)(Wb + (size_t)(r0 + ry) * PDIM + c0 + cb) = *(const uint4*)pk;
  }
}

// ---------------- Kernel 3: bf16 MFMA GEMM, split-K x8, private partials --
// C_z[M][4096] = Xb[M][kq] * Wb^T[kq] ; BM=128 BN=128 BK=64, KQ=512.
// Grid 32 x 4 x 8 = 1024 blocks, 32KB LDS -> ~3 blocks/CU. BM=128 halves
// Wb re-reads (LLC traffic 384->256 MB) and doubles MFMA-per-barrier.
__global__ __launch_bounds__(256, 3) void gemm_kernel(
    const ushort_t* __restrict__ Xb, const ushort_t* __restrict__ Wb,
    float* __restrict__ par, int M) {
  constexpr int Kdim = 4096, Ndim = 4096, KQ = 512;
  __shared__ __align__(16) ushort_t As[128 * 64];
  __shared__ __align__(16) ushort_t Bs[128 * 64];
  const int tid = threadIdx.x;
  const int lane = tid & 63;
  const int w = tid >> 6;
  const int l15 = lane & 15;
  const int quad = lane >> 4;
  const int m0 = blockIdx.y * 128;
  const int n0 = blockIdx.x * 128;
  const int kbase = blockIdx.z * KQ;
  float* outp = par + (size_t)blockIdx.z * ((size_t)512 * Ndim);
  const int arow = lane >> 3;  // 0..7
  const int aslot = lane & 7;

  f32x4 acc[8][2];
#pragma unroll
  for (int mt = 0; mt < 8; ++mt)
#pragma unroll
    for (int nt = 0; nt < 2; ++nt) acc[mt][nt] = (f32x4){0.f, 0.f, 0.f, 0.f};

  for (int it = 0; it < KQ / 64; ++it) {
    const int k0 = kbase + it * 64;
#pragma unroll
    for (int s = w; s < 16; s += 4) {
      const int row = s * 8 + arow;
      const int j = aslot ^ (row & 7);
      async_cp16(Xb + (size_t)(m0 + row) * Kdim + k0 + j * 8,
                 (char*)As + (size_t)s * 1024);
      async_cp16(Wb + (size_t)(n0 + row) * Kdim + k0 + j * 8,
                 (char*)Bs + (size_t)s * 1024);
    }
    __syncthreads();
#pragma unroll
    for (int kk = 0; kk < 64; kk += 32) {
      const int cj = (kk >> 3) + quad;
      bf16x8 bfv[2];
#pragma unroll
      for (int nt = 0; nt < 2; ++nt) {
        const int row = w * 32 + nt * 16 + l15;
        bfv[nt] = *(const bf16x8*)&Bs[(row * 8 + (cj ^ (row & 7))) * 8];
      }
#pragma unroll
      for (int mt = 0; mt < 8; ++mt) {
        const int row = mt * 16 + l15;
        const bf16x8 af = *(const bf16x8*)&As[(row * 8 + (cj ^ (row & 7))) * 8];
        acc[mt][0] = __builtin_amdgcn_mfma_f32_16x16x32_bf16(af, bfv[0],
                                                             acc[mt][0], 0, 0, 0);
        acc[mt][1] = __builtin_amdgcn_mfma_f32_16x16x32_bf16(af, bfv[1],
                                                             acc[mt][1], 0, 0, 0);
      }
    }
    __syncthreads();
  }
  // epilogue: C/D layout col=lane&15 (n), row=quad*4+reg (m)
#pragma unroll
  for (int mt = 0; mt < 8; ++mt) {
#pragma unroll
    for (int nt = 0; nt < 2; ++nt) {
      const int mb = m0 + mt * 16 + quad * 4;
      const int n = n0 + w * 32 + nt * 16 + l15;
#pragma unroll
      for (int r = 0; r < 4; ++r)
        outp[(size_t)(mb + r) * Ndim + n] = acc[mt][nt][r];
    }
  }
}

// ---------------- Kernel 4: sum 8 split-K partials ----------------
__global__ __launch_bounds__(256) void combine_kernel(
    const float4* __restrict__ par, float4* __restrict__ out, int n4) {
  const int i = blockIdx.x * 256 + threadIdx.x;
  if (i >= n4) return;
  float4 s0 = par[i];
  float4 s1 = par[i + n4];
  float4 s2 = par[i + 2 * n4];
  float4 s3 = par[i + 3 * n4];
#pragma unroll
  for (int z = 4; z < 8; ++z) {
    const float4 v = par[i + (size_t)z * n4];
    if (z == 4) { s0.x += v.x; s0.y += v.y; s0.z += v.z; s0.w += v.w; }
    if (z == 5) { s1.x += v.x; s1.y += v.y; s1.z += v.z; s1.w += v.w; }
    if (z == 6) { s2.x += v.x; s2.y += v.y; s2.z += v.z; s2.w += v.w; }
    if (z == 7) { s3.x += v.x; s3.y += v.y; s3.z += v.z; s3.w += v.w; }
  }
  float4 o;
  o.x = (s0.x + s1.x) + (s2.x + s3.x);
  o.y = (s0.y + s1.y) + (s2.y + s3.y);
  o.z = (s0.z + s1.z) + (s2.z + s3.z);
  o.w = (s0.w + s1.w) + (s2.w + s3.w);
  out[i] = o;
}

extern "C" void kernel_launch(void* const* d_in, const int* in_sizes, int n_in,
                              void* d_out, int out_size, void* d_ws,
                              size_t ws_size, hipStream_t stream) {
  const float* x = (const float*)d_in[0];
  const float* V = (const float*)d_in[1];
  const float* alpha = (const float*)d_in[2];
  float* out = (float*)d_out;
  const int M = in_sizes[0] / PDIM;  // 512

  // ws: a(16KB) | Xb bf16 (4MB) | Wb bf16 (32MB) | partials fp32 8x8MB
  float* a_mask = (float*)d_ws;
  ushort_t* Xb = (ushort_t*)((char*)d_ws + 16 * 1024);
  ushort_t* Wb = Xb + (size_t)M * PDIM;
  float* par = (float*)(Wb + (size_t)PDIM * PDIM);

  const int n4x = (M * PDIM) / 4;  // 524288
  prep_kernel<<<1 + (n4x + 255) / 256, 256, 0, stream>>>(alpha, a_mask, x, Xb,
                                                         n4x);
  wmat_kernel<<<dim3(PDIM / 256, PDIM / 32), 256, 0, stream>>>(V, a_mask, Wb);
  gemm_kernel<<<dim3(PDIM / 128, M / 128, 8), 256, 0, stream>>>(Xb, Wb, par, M);
  const int n4o = out_size / 4;
  combine_kernel<<<(n4o + 255) / 256, 256, 0, stream>>>((const float4*)par,
                                                        (float4*)out, n4o);
}

// Round 5
// 164.225 us; speedup vs baseline: 1.0853x; 1.0853x over previous
//
#include <hip/hip_runtime.h>
#include <hip/hip_bf16.h>
#include <stdint.h>

#define PDIM 4096
#define KSEL 3687.0f
#define NITER 50

typedef unsigned short ushort_t;
typedef __attribute__((ext_vector_type(8))) __bf16 bf16x8;
typedef __attribute__((ext_vector_type(4))) float f32x4;

typedef __attribute__((address_space(3))) void lds_void;
typedef __attribute__((address_space(1))) const void glob_void;

__device__ __forceinline__ ushort_t f32_to_bf16_rne(float f) {
  union { float f; uint32_t u; } v; v.f = f;
  uint32_t r = 0x7FFFu + ((v.u >> 16) & 1u);
  return (ushort_t)((v.u + r) >> 16);
}

__device__ __forceinline__ float bf16_to_f32(ushort_t h) {
  union { uint32_t u; float f; } v; v.u = ((uint32_t)h) << 16;
  return v.f;
}

__device__ __forceinline__ void async_cp16(const void* g, void* l) {
  __builtin_amdgcn_global_load_lds((glob_void*)g, (lds_void*)l, 16, 0, 0);
}

// ---------------- Kernel 1: fused Dykstra (block 0) + x->bf16 (rest) ------
__global__ __launch_bounds__(256) void prep_kernel(
    const float* __restrict__ alpha, float* __restrict__ a_out,
    const float* __restrict__ x, ushort_t* __restrict__ Xb, int n4) {
  if (blockIdx.x != 0) {
    const int i = (blockIdx.x - 1) * 256 + threadIdx.x;
    if (i < n4) {
      const float4 v = ((const float4*)x)[i];
      ushort4 o;
      o.x = f32_to_bf16_rne(v.x);
      o.y = f32_to_bf16_rne(v.y);
      o.z = f32_to_bf16_rne(v.z);
      o.w = f32_to_bf16_rne(v.w);
      ((ushort4*)Xb)[i] = o;
    }
    return;
  }
  __shared__ float red[8];
  const int tid = threadIdx.x;
  const int lane = tid & 63;
  const int wv = tid >> 6;
  float xx[16], q[16];
  float p = 0.0f;
#pragma unroll
  for (int i = 0; i < 16; ++i) {
    xx[i] = alpha[i * 256 + tid] * 100.0f;  // s = alpha / 0.01
    q[i] = 0.0f;
  }
  for (int it = 0; it < NITER; ++it) {
    float t[16];
    float loc = 0.0f;
#pragma unroll
    for (int i = 0; i < 16; ++i) { t[i] = xx[i] + p; loc += t[i]; }
#pragma unroll
    for (int off = 32; off > 0; off >>= 1) loc += __shfl_down(loc, off, 64);
    const int slot = (it & 1) * 4;
    if (lane == 0) red[slot + wv] = loc;
    __syncthreads();
    const float tot = red[slot] + red[slot + 1] + red[slot + 2] + red[slot + 3];
    const float corr = (KSEL - tot) * (1.0f / 4096.0f);
    p = -corr;
#pragma unroll
    for (int i = 0; i < 16; ++i) {
      const float y = t[i] + corr;
      const float u = y + q[i];
      const float xn = fminf(fmaxf(u, 0.0f), 1.0f);
      q[i] = u - xn;
      xx[i] = xn;
    }
  }
#pragma unroll
  for (int i = 0; i < 16; ++i) a_out[i * 256 + tid] = xx[i];
}

// ---------------- Kernel 2: materialize W (row-major bf16) ----------------
// R3-proven config: 128x64 tile, 192-row fp32 V band in LDS, pad 67,
// phase-2 stores 128B-per-row segments.
__global__ __launch_bounds__(256) void wmat_kernel(
    const float* __restrict__ V, const float* __restrict__ a,
    ushort_t* __restrict__ Wb) {
  __shared__ float vt[192][67];
  const int t = threadIdx.x;
  const int r0 = blockIdx.x * 128;
  const int c0 = blockIdx.y * 64;
  const int dbase = (r0 - c0 - 63 + 2 * PDIM) & (PDIM - 1);
  const int csub = (t & 15) * 4;
  const int rsub = t >> 4;
#pragma unroll
  for (int i = 0; i < 12; ++i) {
    const int ld = i * 16 + rsub;
    const int d = (dbase + ld) & (PDIM - 1);
    const float av = a[d];
    const float4 vv = *(const float4*)(V + (size_t)d * PDIM + c0 + csub);
    vt[ld][csub + 0] = av * vv.x;
    vt[ld][csub + 1] = av * vv.y;
    vt[ld][csub + 2] = av * vv.z;
    vt[ld][csub + 3] = av * vv.w;
  }
  __syncthreads();
#pragma unroll
  for (int k = 0; k < 4; ++k) {
    const int ry = (t >> 3) + k * 32;
    const int cb = (t & 7) * 8;
    ushort_t pk[8];
#pragma unroll
    for (int j = 0; j < 8; ++j) {
      const int c = cb + j;
      pk[j] = f32_to_bf16_rne(vt[ry - c + 63][c]);
    }
    *(uint4*)(Wb + (size_t)(r0 + ry) * PDIM + c0 + cb) = *(const uint4*)pk;
  }
}

// ---------------- Kernel 3: bf16 MFMA GEMM, split-K x8, XCD-pinned -------
// BM=64 BN=128 BK=64, KQ=512. Grid (z=8, n=32, m=8): z is blockIdx.x ->
// round-robin dispatch puts each z (a private 4MB Wb k-slab) on one XCD's
// L2. Partials written as bf16 in MFMA-blocked order: 8B/lane coalesced.
__global__ __launch_bounds__(256) void gemm_kernel(
    const ushort_t* __restrict__ Xb, const ushort_t* __restrict__ Wb,
    ushort_t* __restrict__ par) {
  constexpr int Kdim = 4096, KQ = 512;
  __shared__ __align__(16) ushort_t As[64 * 64];
  __shared__ __align__(16) ushort_t Bs[128 * 64];
  const int tid = threadIdx.x;
  const int lane = tid & 63;
  const int w = tid >> 6;
  const int l15 = lane & 15;
  const int quad = lane >> 4;
  const int z = blockIdx.x;       // 0..7 -> XCD
  const int nblk = blockIdx.y;    // 0..31
  const int mblk = blockIdx.z;    // 0..7
  const int m0 = mblk * 64;
  const int n0 = nblk * 128;
  const int kbase = z * KQ;
  const int arow = lane >> 3;
  const int aslot = lane & 7;

  f32x4 acc[4][2];
#pragma unroll
  for (int mt = 0; mt < 4; ++mt)
#pragma unroll
    for (int nt = 0; nt < 2; ++nt) acc[mt][nt] = (f32x4){0.f, 0.f, 0.f, 0.f};

  for (int it = 0; it < KQ / 64; ++it) {
    const int k0 = kbase + it * 64;
#pragma unroll
    for (int s = w; s < 8; s += 4) {
      const int row = s * 8 + arow;
      const int j = aslot ^ (row & 7);
      async_cp16(Xb + (size_t)(m0 + row) * Kdim + k0 + j * 8,
                 (char*)As + (size_t)s * 1024);
    }
#pragma unroll
    for (int s = w; s < 16; s += 4) {
      const int row = s * 8 + arow;
      const int j = aslot ^ (row & 7);
      async_cp16(Wb + (size_t)(n0 + row) * Kdim + k0 + j * 8,
                 (char*)Bs + (size_t)s * 1024);
    }
    __syncthreads();
#pragma unroll
    for (int kk = 0; kk < 64; kk += 32) {
      const int cj = (kk >> 3) + quad;
      bf16x8 af[4], bfv[2];
#pragma unroll
      for (int mt = 0; mt < 4; ++mt) {
        const int row = mt * 16 + l15;
        af[mt] = *(const bf16x8*)&As[(row * 8 + (cj ^ (row & 7))) * 8];
      }
#pragma unroll
      for (int nt = 0; nt < 2; ++nt) {
        const int row = w * 32 + nt * 16 + l15;
        bfv[nt] = *(const bf16x8*)&Bs[(row * 8 + (cj ^ (row & 7))) * 8];
      }
#pragma unroll
      for (int mt = 0; mt < 4; ++mt)
#pragma unroll
        for (int nt = 0; nt < 2; ++nt)
          acc[mt][nt] = __builtin_amdgcn_mfma_f32_16x16x32_bf16(
              af[mt], bfv[nt], acc[mt][nt], 0, 0, 0);
    }
    __syncthreads();
  }
  // epilogue: bf16 partials in blocked order, 8B/lane fully coalesced.
  const int tile = nblk * 8 + mblk;  // 0..255
  ushort_t* pbase = par + ((size_t)z * 256 + tile) * 8192;
#pragma unroll
  for (int mt = 0; mt < 4; ++mt) {
#pragma unroll
    for (int nt = 0; nt < 2; ++nt) {
      const int slot = mt * 2 + nt;
      ushort4 o;
      o.x = f32_to_bf16_rne(acc[mt][nt][0]);
      o.y = f32_to_bf16_rne(acc[mt][nt][1]);
      o.z = f32_to_bf16_rne(acc[mt][nt][2]);
      o.w = f32_to_bf16_rne(acc[mt][nt][3]);
      *(ushort4*)(pbase + (size_t)(slot * 256 + tid) * 4) = o;
    }
  }
}

// ---------------- Kernel 4: sum 8 blocked bf16 partials -> row-major out --
// Mirrors gemm thread geometry; the row-major scatter happens exactly once.
__global__ __launch_bounds__(256) void combine_kernel(
    const ushort_t* __restrict__ par, float* __restrict__ out) {
  const int tile = blockIdx.x;  // 0..255
  const int nblk = tile >> 3;
  const int mblk = tile & 7;
  const int m0 = mblk * 64;
  const int n0 = nblk * 128;
  const int tid = threadIdx.x;
  const int lane = tid & 63;
  const int w = tid >> 6;
  const int l15 = lane & 15;
  const int quad = lane >> 4;
#pragma unroll
  for (int slot = 0; slot < 8; ++slot) {
    float s0 = 0.f, s1 = 0.f, s2 = 0.f, s3 = 0.f;
#pragma unroll
    for (int z = 0; z < 8; ++z) {
      const ushort4 v = *(const ushort4*)(par +
          ((size_t)z * 256 + tile) * 8192 + (size_t)(slot * 256 + tid) * 4);
      s0 += bf16_to_f32(v.x);
      s1 += bf16_to_f32(v.y);
      s2 += bf16_to_f32(v.z);
      s3 += bf16_to_f32(v.w);
    }
    const int mt = slot >> 1;
    const int nt = slot & 1;
    const int mb = m0 + mt * 16 + quad * 4;
    const int n = n0 + w * 32 + nt * 16 + l15;
    out[(size_t)(mb + 0) * PDIM + n] = s0;
    out[(size_t)(mb + 1) * PDIM + n] = s1;
    out[(size_t)(mb + 2) * PDIM + n] = s2;
    out[(size_t)(mb + 3) * PDIM + n] = s3;
  }
}

extern "C" void kernel_launch(void* const* d_in, const int* in_sizes, int n_in,
                              void* d_out, int out_size, void* d_ws,
                              size_t ws_size, hipStream_t stream) {
  const float* x = (const float*)d_in[0];
  const float* V = (const float*)d_in[1];
  const float* alpha = (const float*)d_in[2];
  float* out = (float*)d_out;
  const int M = in_sizes[0] / PDIM;  // 512

  // ws: a(16KB) | Xb bf16 (4MB) | Wb bf16 (32MB) | partials bf16 8x4MB
  float* a_mask = (float*)d_ws;
  ushort_t* Xb = (ushort_t*)((char*)d_ws + 16 * 1024);
  ushort_t* Wb = Xb + (size_t)M * PDIM;
  ushort_t* par = Wb + (size_t)PDIM * PDIM;

  const int n4x = (M * PDIM) / 4;  // 524288
  prep_kernel<<<1 + (n4x + 255) / 256, 256, 0, stream>>>(alpha, a_mask, x, Xb,
                                                         n4x);
  wmat_kernel<<<dim3(PDIM / 128, PDIM / 64), 256, 0, stream>>>(V, a_mask, Wb);
  gemm_kernel<<<dim3(8, PDIM / 128, M / 64), 256, 0, stream>>>(Xb, Wb, par);
  combine_kernel<<<256, 256, 0, stream>>>(par, out);
}

// Round 6
// 163.763 us; speedup vs baseline: 1.0884x; 1.0028x over previous
//
#include <hip/hip_runtime.h>
#include <hip/hip_bf16.h>
#include <stdint.h>

#define PDIM 4096
#define KSEL 3687.0f
#define NITER 50

typedef unsigned short ushort_t;
typedef __attribute__((ext_vector_type(8))) __bf16 bf16x8;
typedef __attribute__((ext_vector_type(4))) float f32x4;

typedef __attribute__((address_space(3))) void lds_void;
typedef __attribute__((address_space(1))) const void glob_void;

__device__ __forceinline__ ushort_t f32_to_bf16_rne(float f) {
  union { float f; uint32_t u; } v; v.f = f;
  uint32_t r = 0x7FFFu + ((v.u >> 16) & 1u);
  return (ushort_t)((v.u + r) >> 16);
}

__device__ __forceinline__ float bf16_to_f32(ushort_t h) {
  union { uint32_t u; float f; } v; v.u = ((uint32_t)h) << 16;
  return v.f;
}

__device__ __forceinline__ void async_cp16(const void* g, void* l) {
  __builtin_amdgcn_global_load_lds((glob_void*)g, (lds_void*)l, 16, 0, 0);
}

// ---------------- Kernel 1: fused Dykstra (block 0) + x->bf16 (rest) ------
__global__ __launch_bounds__(256) void prep_kernel(
    const float* __restrict__ alpha, float* __restrict__ a_out,
    const float* __restrict__ x, ushort_t* __restrict__ Xb, int n4) {
  if (blockIdx.x != 0) {
    const int i = (blockIdx.x - 1) * 256 + threadIdx.x;
    if (i < n4) {
      const float4 v = ((const float4*)x)[i];
      ushort4 o;
      o.x = f32_to_bf16_rne(v.x);
      o.y = f32_to_bf16_rne(v.y);
      o.z = f32_to_bf16_rne(v.z);
      o.w = f32_to_bf16_rne(v.w);
      ((ushort4*)Xb)[i] = o;
    }
    return;
  }
  __shared__ float red[8];
  const int tid = threadIdx.x;
  const int lane = tid & 63;
  const int wv = tid >> 6;
  float xx[16], q[16];
  float p = 0.0f;
#pragma unroll
  for (int i = 0; i < 16; ++i) {
    xx[i] = alpha[i * 256 + tid] * 100.0f;  // s = alpha / 0.01
    q[i] = 0.0f;
  }
  for (int it = 0; it < NITER; ++it) {
    float t[16];
    float loc = 0.0f;
#pragma unroll
    for (int i = 0; i < 16; ++i) { t[i] = xx[i] + p; loc += t[i]; }
#pragma unroll
    for (int off = 32; off > 0; off >>= 1) loc += __shfl_down(loc, off, 64);
    const int slot = (it & 1) * 4;
    if (lane == 0) red[slot + wv] = loc;
    __syncthreads();
    const float tot = red[slot] + red[slot + 1] + red[slot + 2] + red[slot + 3];
    const float corr = (KSEL - tot) * (1.0f / 4096.0f);
    p = -corr;
#pragma unroll
    for (int i = 0; i < 16; ++i) {
      const float y = t[i] + corr;
      const float u = y + q[i];
      const float xn = fminf(fmaxf(u, 0.0f), 1.0f);
      q[i] = u - xn;
      xx[i] = xn;
    }
  }
#pragma unroll
  for (int i = 0; i < 16; ++i) a_out[i * 256 + tid] = xx[i];
}

// ---------------- Kernel 2: materialize W (row-major bf16) ----------------
// R3-proven config: 128x64 tile, 192-row fp32 V band in LDS, pad 67,
// phase-2 stores 128B-per-row segments.
__global__ __launch_bounds__(256) void wmat_kernel(
    const float* __restrict__ V, const float* __restrict__ a,
    ushort_t* __restrict__ Wb) {
  __shared__ float vt[192][67];
  const int t = threadIdx.x;
  const int r0 = blockIdx.x * 128;
  const int c0 = blockIdx.y * 64;
  const int dbase = (r0 - c0 - 63 + 2 * PDIM) & (PDIM - 1);
  const int csub = (t & 15) * 4;
  const int rsub = t >> 4;
#pragma unroll
  for (int i = 0; i < 12; ++i) {
    const int ld = i * 16 + rsub;
    const int d = (dbase + ld) & (PDIM - 1);
    const float av = a[d];
    const float4 vv = *(const float4*)(V + (size_t)d * PDIM + c0 + csub);
    vt[ld][csub + 0] = av * vv.x;
    vt[ld][csub + 1] = av * vv.y;
    vt[ld][csub + 2] = av * vv.z;
    vt[ld][csub + 3] = av * vv.w;
  }
  __syncthreads();
#pragma unroll
  for (int k = 0; k < 4; ++k) {
    const int ry = (t >> 3) + k * 32;
    const int cb = (t & 7) * 8;
    ushort_t pk[8];
#pragma unroll
    for (int j = 0; j < 8; ++j) {
      const int c = cb + j;
      pk[j] = f32_to_bf16_rne(vt[ry - c + 63][c]);
    }
    *(uint4*)(Wb + (size_t)(r0 + ry) * PDIM + c0 + cb) = *(const uint4*)pk;
  }
}

// ---------------- Kernel 3: bf16 MFMA GEMM, split-K x8, BM=BN=128 --------
// C_z = Xb[.,kq] * Wb^T[.,kq]; BM=128 BN=128 BK=64, KQ=512.
// Grid (z=8, n=32, m=4) = 1024 blocks; z fastest -> XCD-pinned k-slabs.
// LLC staging traffic: 32x4MB (A) + 4x32MB (B) = 256 MB (was 384 at BM=64).
// Partials: bf16, MFMA-blocked order, 8B/lane coalesced stores.
__global__ __launch_bounds__(256, 3) void gemm_kernel(
    const ushort_t* __restrict__ Xb, const ushort_t* __restrict__ Wb,
    ushort_t* __restrict__ par) {
  constexpr int Kdim = 4096, KQ = 512;
  __shared__ __align__(16) ushort_t As[128 * 64];
  __shared__ __align__(16) ushort_t Bs[128 * 64];
  const int tid = threadIdx.x;
  const int lane = tid & 63;
  const int w = tid >> 6;
  const int l15 = lane & 15;
  const int quad = lane >> 4;
  const int z = blockIdx.x;     // 0..7 -> XCD-pinned k-slab
  const int nblk = blockIdx.y;  // 0..31
  const int mblk = blockIdx.z;  // 0..3
  const int m0 = mblk * 128;
  const int n0 = nblk * 128;
  const int kbase = z * KQ;
  const int arow = lane >> 3;
  const int aslot = lane & 7;

  f32x4 acc[8][2];
#pragma unroll
  for (int mt = 0; mt < 8; ++mt)
#pragma unroll
    for (int nt = 0; nt < 2; ++nt) acc[mt][nt] = (f32x4){0.f, 0.f, 0.f, 0.f};

  for (int it = 0; it < KQ / 64; ++it) {
    const int k0 = kbase + it * 64;
#pragma unroll
    for (int s = w; s < 16; s += 4) {
      const int row = s * 8 + arow;
      const int j = aslot ^ (row & 7);
      async_cp16(Xb + (size_t)(m0 + row) * Kdim + k0 + j * 8,
                 (char*)As + (size_t)s * 1024);
      async_cp16(Wb + (size_t)(n0 + row) * Kdim + k0 + j * 8,
                 (char*)Bs + (size_t)s * 1024);
    }
    __syncthreads();
#pragma unroll
    for (int kk = 0; kk < 64; kk += 32) {
      const int cj = (kk >> 3) + quad;
      bf16x8 bfv[2];
#pragma unroll
      for (int nt = 0; nt < 2; ++nt) {
        const int row = w * 32 + nt * 16 + l15;
        bfv[nt] = *(const bf16x8*)&Bs[(row * 8 + (cj ^ (row & 7))) * 8];
      }
#pragma unroll
      for (int mt = 0; mt < 8; ++mt) {
        const int row = mt * 16 + l15;
        const bf16x8 af = *(const bf16x8*)&As[(row * 8 + (cj ^ (row & 7))) * 8];
        acc[mt][0] = __builtin_amdgcn_mfma_f32_16x16x32_bf16(af, bfv[0],
                                                             acc[mt][0], 0, 0, 0);
        acc[mt][1] = __builtin_amdgcn_mfma_f32_16x16x32_bf16(af, bfv[1],
                                                             acc[mt][1], 0, 0, 0);
      }
    }
    __syncthreads();
  }
  // epilogue: bf16 partials in blocked order, 8B/lane coalesced.
  const int tile = nblk * 4 + mblk;  // 0..127
  ushort_t* pbase = par + ((size_t)z * 128 + tile) * 16384;
#pragma unroll
  for (int mt = 0; mt < 8; ++mt) {
#pragma unroll
    for (int nt = 0; nt < 2; ++nt) {
      const int slot = mt * 2 + nt;
      ushort4 o;
      o.x = f32_to_bf16_rne(acc[mt][nt][0]);
      o.y = f32_to_bf16_rne(acc[mt][nt][1]);
      o.z = f32_to_bf16_rne(acc[mt][nt][2]);
      o.w = f32_to_bf16_rne(acc[mt][nt][3]);
      *(ushort4*)(pbase + (size_t)(slot * 256 + tid) * 4) = o;
    }
  }
}

// ---------------- Kernel 4: sum 8 blocked bf16 partials -> row-major out --
// Grid = 128 tiles x 2 halves; mirrors gemm thread geometry.
__global__ __launch_bounds__(256) void combine_kernel(
    const ushort_t* __restrict__ par, float* __restrict__ out) {
  const int tile = blockIdx.x >> 1;  // 0..127
  const int h = blockIdx.x & 1;
  const int nblk = tile >> 2;
  const int mblk = tile & 3;
  const int m0 = mblk * 128;
  const int n0 = nblk * 128;
  const int tid = threadIdx.x;
  const int lane = tid & 63;
  const int w = tid >> 6;
  const int l15 = lane & 15;
  const int quad = lane >> 4;
#pragma unroll
  for (int ss = 0; ss < 8; ++ss) {
    const int slot = h * 8 + ss;
    float s0 = 0.f, s1 = 0.f, s2 = 0.f, s3 = 0.f;
#pragma unroll
    for (int z = 0; z < 8; ++z) {
      const ushort4 v = *(const ushort4*)(par +
          ((size_t)z * 128 + tile) * 16384 + (size_t)(slot * 256 + tid) * 4);
      s0 += bf16_to_f32(v.x);
      s1 += bf16_to_f32(v.y);
      s2 += bf16_to_f32(v.z);
      s3 += bf16_to_f32(v.w);
    }
    const int mt = slot >> 1;
    const int nt = slot & 1;
    const int mb = m0 + mt * 16 + quad * 4;
    const int n = n0 + w * 32 + nt * 16 + l15;
    out[(size_t)(mb + 0) * PDIM + n] = s0;
    out[(size_t)(mb + 1) * PDIM + n] = s1;
    out[(size_t)(mb + 2) * PDIM + n] = s2;
    out[(size_t)(mb + 3) * PDIM + n] = s3;
  }
}

extern "C" void kernel_launch(void* const* d_in, const int* in_sizes, int n_in,
                              void* d_out, int out_size, void* d_ws,
                              size_t ws_size, hipStream_t stream) {
  const float* x = (const float*)d_in[0];
  const float* V = (const float*)d_in[1];
  const float* alpha = (const float*)d_in[2];
  float* out = (float*)d_out;
  const int M = in_sizes[0] / PDIM;  // 512

  // ws: a(16KB) | Xb bf16 (4MB) | Wb bf16 (32MB) | partials bf16 8x4MB
  float* a_mask = (float*)d_ws;
  ushort_t* Xb = (ushort_t*)((char*)d_ws + 16 * 1024);
  ushort_t* Wb = Xb + (size_t)M * PDIM;
  ushort_t* par = Wb + (size_t)PDIM * PDIM;

  const int n4x = (M * PDIM) / 4;  // 524288
  prep_kernel<<<1 + (n4x + 255) / 256, 256, 0, stream>>>(alpha, a_mask, x, Xb,
                                                         n4x);
  wmat_kernel<<<dim3(PDIM / 128, PDIM / 64), 256, 0, stream>>>(V, a_mask, Wb);
  gemm_kernel<<<dim3(8, PDIM / 128, M / 128), 256, 0, stream>>>(Xb, Wb, par);
  combine_kernel<<<256, 256, 0, stream>>>(par, out);
}

// Round 7
// 157.064 us; speedup vs baseline: 1.1348x; 1.0427x over previous
//
#include <hip/hip_runtime.h>
#include <hip/hip_bf16.h>
#include <stdint.h>

#define PDIM 4096
#define KSEL 3687.0f
#define NITER 50

typedef unsigned short ushort_t;
typedef __attribute__((ext_vector_type(8))) __bf16 bf16x8;
typedef __attribute__((ext_vector_type(4))) float f32x4;

typedef __attribute__((address_space(3))) void lds_void;
typedef __attribute__((address_space(1))) const void glob_void;

__device__ __forceinline__ ushort_t f32_to_bf16_rne(float f) {
  union { float f; uint32_t u; } v; v.f = f;
  uint32_t r = 0x7FFFu + ((v.u >> 16) & 1u);
  return (ushort_t)((v.u + r) >> 16);
}

__device__ __forceinline__ float bf16_to_f32(ushort_t h) {
  union { uint32_t u; float f; } v; v.u = ((uint32_t)h) << 16;
  return v.f;
}

__device__ __forceinline__ void async_cp16(const void* g, void* l) {
  __builtin_amdgcn_global_load_lds((glob_void*)g, (lds_void*)l, 16, 0, 0);
}

// ---------------- Kernel 1: fused Dykstra (block 0) + x->bf16 (rest) ------
__global__ __launch_bounds__(256) void prep_kernel(
    const float* __restrict__ alpha, float* __restrict__ a_out,
    const float* __restrict__ x, ushort_t* __restrict__ Xb, int n4) {
  if (blockIdx.x != 0) {
    const int i = (blockIdx.x - 1) * 256 + threadIdx.x;
    if (i < n4) {
      const float4 v = ((const float4*)x)[i];
      ushort4 o;
      o.x = f32_to_bf16_rne(v.x);
      o.y = f32_to_bf16_rne(v.y);
      o.z = f32_to_bf16_rne(v.z);
      o.w = f32_to_bf16_rne(v.w);
      ((ushort4*)Xb)[i] = o;
    }
    return;
  }
  __shared__ float red[8];
  const int tid = threadIdx.x;
  const int lane = tid & 63;
  const int wv = tid >> 6;
  float xx[16], q[16];
  float p = 0.0f;
#pragma unroll
  for (int i = 0; i < 16; ++i) {
    xx[i] = alpha[i * 256 + tid] * 100.0f;  // s = alpha / 0.01
    q[i] = 0.0f;
  }
  for (int it = 0; it < NITER; ++it) {
    float t[16];
    float loc = 0.0f;
#pragma unroll
    for (int i = 0; i < 16; ++i) { t[i] = xx[i] + p; loc += t[i]; }
#pragma unroll
    for (int off = 32; off > 0; off >>= 1) loc += __shfl_down(loc, off, 64);
    const int slot = (it & 1) * 4;
    if (lane == 0) red[slot + wv] = loc;
    __syncthreads();
    const float tot = red[slot] + red[slot + 1] + red[slot + 2] + red[slot + 3];
    const float corr = (KSEL - tot) * (1.0f / 4096.0f);
    p = -corr;
#pragma unroll
    for (int i = 0; i < 16; ++i) {
      const float y = t[i] + corr;
      const float u = y + q[i];
      const float xn = fminf(fmaxf(u, 0.0f), 1.0f);
      q[i] = u - xn;
      xx[i] = xn;
    }
  }
#pragma unroll
  for (int i = 0; i < 16; ++i) a_out[i * 256 + tid] = xx[i];
}

// ---------------- Kernel 2: materialize W (row-major bf16) ----------------
// R3-proven config: 128x64 tile, 192-row fp32 V band in LDS, pad 67,
// phase-2 stores 128B-per-row segments.
__global__ __launch_bounds__(256) void wmat_kernel(
    const float* __restrict__ V, const float* __restrict__ a,
    ushort_t* __restrict__ Wb) {
  __shared__ float vt[192][67];
  const int t = threadIdx.x;
  const int r0 = blockIdx.x * 128;
  const int c0 = blockIdx.y * 64;
  const int dbase = (r0 - c0 - 63 + 2 * PDIM) & (PDIM - 1);
  const int csub = (t & 15) * 4;
  const int rsub = t >> 4;
#pragma unroll
  for (int i = 0; i < 12; ++i) {
    const int ld = i * 16 + rsub;
    const int d = (dbase + ld) & (PDIM - 1);
    const float av = a[d];
    const float4 vv = *(const float4*)(V + (size_t)d * PDIM + c0 + csub);
    vt[ld][csub + 0] = av * vv.x;
    vt[ld][csub + 1] = av * vv.y;
    vt[ld][csub + 2] = av * vv.z;
    vt[ld][csub + 3] = av * vv.w;
  }
  __syncthreads();
#pragma unroll
  for (int k = 0; k < 4; ++k) {
    const int ry = (t >> 3) + k * 32;
    const int cb = (t & 7) * 8;
    ushort_t pk[8];
#pragma unroll
    for (int j = 0; j < 8; ++j) {
      const int c = cb + j;
      pk[j] = f32_to_bf16_rne(vt[ry - c + 63][c]);
    }
    *(uint4*)(Wb + (size_t)(r0 + ry) * PDIM + c0 + cb) = *(const uint4*)pk;
  }
}

// ---------------- Kernel 3: bf16 MFMA GEMM, split-K x4, BM=BN=128 --------
// C_z = Xb[.,kq] * Wb^T[.,kq]; BM=128 BN=128 BK=64, KQ=1024.
// Grid (z=4, n=32, m=4) = 512 blocks -> 2 blocks/CU (co-residency probe).
// Partial traffic halves vs z=8: 16MB write + 16MB read.
__global__ __launch_bounds__(256, 3) void gemm_kernel(
    const ushort_t* __restrict__ Xb, const ushort_t* __restrict__ Wb,
    ushort_t* __restrict__ par) {
  constexpr int Kdim = 4096, KQ = 1024;
  __shared__ __align__(16) ushort_t As[128 * 64];
  __shared__ __align__(16) ushort_t Bs[128 * 64];
  const int tid = threadIdx.x;
  const int lane = tid & 63;
  const int w = tid >> 6;
  const int l15 = lane & 15;
  const int quad = lane >> 4;
  const int z = blockIdx.x;     // 0..3
  const int nblk = blockIdx.y;  // 0..31
  const int mblk = blockIdx.z;  // 0..3
  const int m0 = mblk * 128;
  const int n0 = nblk * 128;
  const int kbase = z * KQ;
  const int arow = lane >> 3;
  const int aslot = lane & 7;

  f32x4 acc[8][2];
#pragma unroll
  for (int mt = 0; mt < 8; ++mt)
#pragma unroll
    for (int nt = 0; nt < 2; ++nt) acc[mt][nt] = (f32x4){0.f, 0.f, 0.f, 0.f};

  for (int it = 0; it < KQ / 64; ++it) {
    const int k0 = kbase + it * 64;
#pragma unroll
    for (int s = w; s < 16; s += 4) {
      const int row = s * 8 + arow;
      const int j = aslot ^ (row & 7);
      async_cp16(Xb + (size_t)(m0 + row) * Kdim + k0 + j * 8,
                 (char*)As + (size_t)s * 1024);
      async_cp16(Wb + (size_t)(n0 + row) * Kdim + k0 + j * 8,
                 (char*)Bs + (size_t)s * 1024);
    }
    __syncthreads();
#pragma unroll
    for (int kk = 0; kk < 64; kk += 32) {
      const int cj = (kk >> 3) + quad;
      bf16x8 bfv[2];
#pragma unroll
      for (int nt = 0; nt < 2; ++nt) {
        const int row = w * 32 + nt * 16 + l15;
        bfv[nt] = *(const bf16x8*)&Bs[(row * 8 + (cj ^ (row & 7))) * 8];
      }
#pragma unroll
      for (int mt = 0; mt < 8; ++mt) {
        const int row = mt * 16 + l15;
        const bf16x8 af = *(const bf16x8*)&As[(row * 8 + (cj ^ (row & 7))) * 8];
        acc[mt][0] = __builtin_amdgcn_mfma_f32_16x16x32_bf16(af, bfv[0],
                                                             acc[mt][0], 0, 0, 0);
        acc[mt][1] = __builtin_amdgcn_mfma_f32_16x16x32_bf16(af, bfv[1],
                                                             acc[mt][1], 0, 0, 0);
      }
    }
    __syncthreads();
  }
  // epilogue: bf16 partials in blocked order, 8B/lane coalesced.
  const int tile = nblk * 4 + mblk;  // 0..127
  ushort_t* pbase = par + ((size_t)z * 128 + tile) * 16384;
#pragma unroll
  for (int mt = 0; mt < 8; ++mt) {
#pragma unroll
    for (int nt = 0; nt < 2; ++nt) {
      const int slot = mt * 2 + nt;
      ushort4 o;
      o.x = f32_to_bf16_rne(acc[mt][nt][0]);
      o.y = f32_to_bf16_rne(acc[mt][nt][1]);
      o.z = f32_to_bf16_rne(acc[mt][nt][2]);
      o.w = f32_to_bf16_rne(acc[mt][nt][3]);
      *(ushort4*)(pbase + (size_t)(slot * 256 + tid) * 4) = o;
    }
  }
}

// ---------------- Kernel 4: sum 4 blocked bf16 partials -> row-major out --
// Grid = 128 tiles x 4 quarters (512 blocks, 2/CU); mirrors gemm geometry.
__global__ __launch_bounds__(256) void combine_kernel(
    const ushort_t* __restrict__ par, float* __restrict__ out) {
  const int tile = blockIdx.x >> 2;  // 0..127
  const int qh = blockIdx.x & 3;
  const int nblk = tile >> 2;
  const int mblk = tile & 3;
  const int m0 = mblk * 128;
  const int n0 = nblk * 128;
  const int tid = threadIdx.x;
  const int lane = tid & 63;
  const int w = tid >> 6;
  const int l15 = lane & 15;
  const int quad = lane >> 4;
#pragma unroll
  for (int ss = 0; ss < 4; ++ss) {
    const int slot = qh * 4 + ss;
    float s0 = 0.f, s1 = 0.f, s2 = 0.f, s3 = 0.f;
#pragma unroll
    for (int z = 0; z < 4; ++z) {
      const ushort4 v = *(const ushort4*)(par +
          ((size_t)z * 128 + tile) * 16384 + (size_t)(slot * 256 + tid) * 4);
      s0 += bf16_to_f32(v.x);
      s1 += bf16_to_f32(v.y);
      s2 += bf16_to_f32(v.z);
      s3 += bf16_to_f32(v.w);
    }
    const int mt = slot >> 1;
    const int nt = slot & 1;
    const int mb = m0 + mt * 16 + quad * 4;
    const int n = n0 + w * 32 + nt * 16 + l15;
    out[(size_t)(mb + 0) * PDIM + n] = s0;
    out[(size_t)(mb + 1) * PDIM + n] = s1;
    out[(size_t)(mb + 2) * PDIM + n] = s2;
    out[(size_t)(mb + 3) * PDIM + n] = s3;
  }
}

extern "C" void kernel_launch(void* const* d_in, const int* in_sizes, int n_in,
                              void* d_out, int out_size, void* d_ws,
                              size_t ws_size, hipStream_t stream) {
  const float* x = (const float*)d_in[0];
  const float* V = (const float*)d_in[1];
  const float* alpha = (const float*)d_in[2];
  float* out = (float*)d_out;
  const int M = in_sizes[0] / PDIM;  // 512

  // ws: a(16KB) | Xb bf16 (4MB) | Wb bf16 (32MB) | partials bf16 4x4MB
  float* a_mask = (float*)d_ws;
  ushort_t* Xb = (ushort_t*)((char*)d_ws + 16 * 1024);
  ushort_t* Wb = Xb + (size_t)M * PDIM;
  ushort_t* par = Wb + (size_t)PDIM * PDIM;

  const int n4x = (M * PDIM) / 4;  // 524288
  prep_kernel<<<1 + (n4x + 255) / 256, 256, 0, stream>>>(alpha, a_mask, x, Xb,
                                                         n4x);
  wmat_kernel<<<dim3(PDIM / 128, PDIM / 64), 256, 0, stream>>>(V, a_mask, Wb);
  gemm_kernel<<<dim3(4, PDIM / 128, M / 128), 256, 0, stream>>>(Xb, Wb, par);
  combine_kernel<<<512, 256, 0, stream>>>(par, out);
}